// Round 12
// baseline (513.129 us; speedup 1.0000x reference)
//
#include <hip/hip_runtime.h>

#define H 1024
#define S 2048
#define NH 16
#define HD 64
#define ISZ 4096

typedef __attribute__((ext_vector_type(8))) short s8v;   // 8 bf16 = 16B
typedef __attribute__((ext_vector_type(4))) short s4v;   // 4 bf16 = 8B
typedef __attribute__((ext_vector_type(4))) float f4v;

__device__ __forceinline__ short f2bf(float f) {
    unsigned u = __builtin_bit_cast(unsigned, f);
    unsigned r = (u + 0x7FFFu + ((u >> 16) & 1u)) >> 16;
    return (short)r;
}
__device__ __forceinline__ float bf2f(short s) {
    unsigned u = ((unsigned)(unsigned short)s) << 16;
    return __builtin_bit_cast(float, u);
}

__device__ __forceinline__ void gload_lds16(const short* g, short* l) {
    __builtin_amdgcn_global_load_lds(
        (const __attribute__((address_space(1))) void*)g,
        (__attribute__((address_space(3))) void*)l, 16, 0, 0);
}

// ---------------- mega-preamble ----------------
struct PreArgs {
    const void* hid; const void* ctx;
    const void* sanw; const void* canw; const void* mlpnw;
    const void* w[11];
    short* hidc; short* ctxc; short* xn;
    short* wT[11];
    float* rowss;        // 2*S floats, zeroed here
    int* flag_out;
};

// transpose 32x32 tile; dst row = n*rmul + roff; optional gamma fold on K dim
__device__ __forceinline__ void tr_tile(const void* src, short* dst, int K, int N,
                                        int k0, int n0, int rmul, int roff,
                                        int isbf, const void* gamma, float* tile) {
    int t = threadIdx.x;
    int c = t & 31, r0 = t >> 5;
    if (isbf) {
        const short* s = (const short*)src;
#pragma unroll
        for (int i = 0; i < 4; i++)
            tile[(r0 + i * 8) * 33 + c] = bf2f(s[(k0 + r0 + i * 8) * N + n0 + c]);
    } else {
        const float* s = (const float*)src;
#pragma unroll
        for (int i = 0; i < 4; i++)
            tile[(r0 + i * 8) * 33 + c] = s[(k0 + r0 + i * 8) * N + n0 + c];
    }
    float gval = 1.f;
    if (gamma)
        gval = isbf ? bf2f(((const short*)gamma)[k0 + c]) : ((const float*)gamma)[k0 + c];
    __syncthreads();
#pragma unroll
    for (int i = 0; i < 4; i++)
        dst[((n0 + r0 + i * 8) * rmul + roff) * K + k0 + c] = f2bf(tile[c * 33 + r0 + i * 8] * gval);
}

__global__ __launch_bounds__(256) void preamble_kernel(PreArgs pa) {
    __shared__ float tile[32 * 33];
    __shared__ float red[4];
    int b = blockIdx.x;
    int t = threadIdx.x;
    int isbf = (((const unsigned*)pa.sanw)[0] == 0x3F803F80u);
    if (blockIdx.x == 0 && t == 0) pa.flag_out[0] = isbf;

    if (b < 2048) {                       // hid convert + sa-rmsnorm -> xn
        int row = b;
        float xf[4];
        if (isbf) {
            s4v xv = *(const s4v*)((const short*)pa.hid + row * H + t * 4);
#pragma unroll
            for (int j = 0; j < 4; j++) xf[j] = bf2f(xv[j]);
        } else {
            const float* s = (const float*)pa.hid + row * H + t * 4;
#pragma unroll
            for (int j = 0; j < 4; j++) xf[j] = s[j];
        }
        float ss = 0.f;
        s4v cv;
#pragma unroll
        for (int j = 0; j < 4; j++) { cv[j] = f2bf(xf[j]); xf[j] = bf2f(cv[j]); ss += xf[j] * xf[j]; }
        *(s4v*)(pa.hidc + row * H + t * 4) = cv;
        int lane = t & 63, wid = t >> 6;
#pragma unroll
        for (int off = 32; off >= 1; off >>= 1) ss += __shfl_xor(ss, off);
        if (lane == 0) red[wid] = ss;
        __syncthreads();
        float tot = red[0] + red[1] + red[2] + red[3];
        float scale = rsqrtf(tot * (1.f / (float)H) + 1e-6f);
        float wv[4];
        if (isbf) {
            s4v wq = *(const s4v*)((const short*)pa.sanw + t * 4);
#pragma unroll
            for (int j = 0; j < 4; j++) wv[j] = bf2f(wq[j]);
        } else {
            const float* s = (const float*)pa.sanw + t * 4;
#pragma unroll
            for (int j = 0; j < 4; j++) wv[j] = s[j];
        }
        s4v ov;
#pragma unroll
        for (int j = 0; j < 4; j++) ov[j] = f2bf(xf[j] * scale * wv[j]);
        *(s4v*)(pa.xn + row * H + t * 4) = ov;
        return;
    }
    b -= 2048;
    if (b < 1024) {                       // ctx convert
        int i8 = b * 2048 + t * 8;
        if (isbf) {
            *(s8v*)(pa.ctxc + i8) = *(const s8v*)((const short*)pa.ctx + i8);
        } else {
            const float* s = (const float*)pa.ctx;
            s8v o;
#pragma unroll
            for (int j = 0; j < 8; j++) o[j] = f2bf(s[i8 + j]);
            *(s8v*)(pa.ctxc + i8) = o;
        }
        return;
    }
    b -= 1024;
    if (b < 2) {                          // zero rowss (2*S floats)
        f4v z = (f4v){0.f, 0.f, 0.f, 0.f};
        *(f4v*)(pa.rowss + b * 2048 + t * 8) = z;
        *(f4v*)(pa.rowss + b * 2048 + t * 8 + 4) = z;
        return;
    }
    b -= 2;
    if (b < 8 * 1024) {                   // 8 HxH transposes (γ_ca folded into ca-wq)
        int w = b >> 10, tl = b & 1023;
        const void* g = (w == 4) ? pa.canw : nullptr;
        tr_tile(pa.w[w], pa.wT[w], H, H, (tl & 31) * 32, (tl >> 5) * 32, 1, 0, isbf, g, tile);
        return;
    }
    b -= 8 * 1024;
    if (b < 2 * 4096) {                   // wg, wu interleaved, γ_mlp folded
        int w = 8 + (b >> 12), tl = b & 4095;
        tr_tile(pa.w[w], pa.wT[8], H, ISZ, (tl & 31) * 32, (tl >> 5) * 32, 2, w - 8, isbf, pa.mlpnw, tile);
        return;
    }
    b -= 2 * 4096;
    {                                     // wd
        tr_tile(pa.w[10], pa.wT[10], ISZ, H, (b & 127) * 32, (b >> 7) * 32, 1, 0, isbf, nullptr, tile);
    }
}

// ---------------- GEMM (B-transposed), fused epilogues ----------------
// A = (blockIdx.y < split) ? A0 : A1.
// scaleA: per-row sumsq; rows scaled by rsqrt(ss/1024+eps) when blockIdx.y<split.
// ssout: atomic per-row sumsq accumulation of the (res-added) fp32 outputs.
// vtbuf/vcol0: transposed store of cols>=vcol0. silu_out: interleaved g/u silu.
template <int BM_, int BN_>
__global__ __launch_bounds__(256, 2) void gemm_bt_kernel(
    const short* __restrict__ A0, const short* __restrict__ A1, int split, int lda,
    const short* __restrict__ Bt,
    void* __restrict__ C, int ldc, int K,
    const short* __restrict__ res,
    const int* __restrict__ dtype_flag,
    short* __restrict__ vtbuf, int vcol0,
    short* __restrict__ silu_out,
    const float* __restrict__ scaleA, float* __restrict__ ssout) {

    constexpr int MC = BM_ / 32;
    constexpr int NC = BN_ / 32;

    const short* A = (blockIdx.y < split) ? A0 : A1;
    int m0 = blockIdx.x * BM_;
    int n0 = blockIdx.y * BN_;

    __shared__ short As[2 * BM_ * 32];   // [half][row][32], 64B rows
    __shared__ short Bs[2 * BN_ * 32];

    int t = threadIdx.x;
    int lane = t & 63, wid = t >> 6;
    int quad = lane >> 4, l15 = lane & 15;
    int wr = wid >> 1, wc = wid & 1;

    f4v acc[MC][NC] = {};

    int ld4 = lane >> 2, lc8 = (lane & 3) * 8;

    for (int k0 = 0; k0 < K; k0 += 64) {
#pragma unroll
        for (int h = 0; h < 2; h++) {
#pragma unroll
            for (int i = 0; i < BM_ / 64; i++)
                gload_lds16(A + (m0 + wid * (BM_ / 4) + i * 16 + ld4) * lda + k0 + h * 32 + lc8,
                            As + h * BM_ * 32 + (wid * (BM_ / 4) + i * 16) * 32);
#pragma unroll
            for (int i = 0; i < BN_ / 64; i++)
                gload_lds16(Bt + (n0 + wid * (BN_ / 4) + i * 16 + ld4) * K + k0 + h * 32 + lc8,
                            Bs + h * BN_ * 32 + (wid * (BN_ / 4) + i * 16) * 32);
        }
        __syncthreads();

#pragma unroll
        for (int h = 0; h < 2; h++) {
            s8v af[MC], bfv[NC];
#pragma unroll
            for (int mc = 0; mc < MC; mc++)
                af[mc] = *(const s8v*)(As + h * BM_ * 32 + (wr * (BM_ / 2) + mc * 16 + l15) * 32 + quad * 8);
#pragma unroll
            for (int nc = 0; nc < NC; nc++)
                bfv[nc] = *(const s8v*)(Bs + h * BN_ * 32 + (wc * (BN_ / 2) + nc * 16 + l15) * 32 + quad * 8);

#pragma unroll
            for (int mc = 0; mc < MC; mc++)
#pragma unroll
                for (int nc = 0; nc < NC; nc++)
                    acc[mc][nc] = __builtin_amdgcn_mfma_f32_16x16x32_bf16(af[mc], bfv[nc], acc[mc][nc], 0, 0, 0);
        }
        __syncthreads();
    }

    bool do_scale = (scaleA != nullptr) && ((int)blockIdx.y < split);

    if (silu_out) {
#pragma unroll
        for (int mc = 0; mc < MC; mc++) {
#pragma unroll
            for (int nc = 0; nc < NC; nc++) {
                int row = m0 + wr * (BM_ / 2) + mc * 16 + quad * 4;
                int col = n0 + wc * (BN_ / 2) + nc * 16 + l15;
#pragma unroll
                for (int r = 0; r < 4; r++) {
                    float v = acc[mc][nc][r];
                    if (do_scale) v *= rsqrtf(scaleA[row + r] * (1.f / 1024.f) + 1e-6f);
                    float other = __shfl_xor(v, 1);
                    if ((l15 & 1) == 0) {
                        float sig = 1.f / (1.f + __expf(-v));
                        silu_out[(row + r) * ISZ + (col >> 1)] = f2bf(v * sig * other);
                    }
                }
            }
        }
        return;
    }

    int out_fp32 = (dtype_flag != nullptr) && (dtype_flag[0] == 0);
    float sq[MC][4] = {};

#pragma unroll
    for (int mc = 0; mc < MC; mc++) {
#pragma unroll
        for (int nc = 0; nc < NC; nc++) {
            int row = m0 + wr * (BM_ / 2) + mc * 16 + quad * 4;
            int col = n0 + wc * (BN_ / 2) + nc * 16 + l15;
#pragma unroll
            for (int r = 0; r < 4; r++) {
                float vf = acc[mc][nc][r];
                if (do_scale) vf *= rsqrtf(scaleA[row + r] * (1.f / 1024.f) + 1e-6f);
                if (res) vf += bf2f(res[(row + r) * ldc + col]);
                if (ssout) sq[mc][r] += vf * vf;
                if (vtbuf && col >= vcol0)
                    vtbuf[(col - vcol0) * S + row + r] = f2bf(vf);
                else if (out_fp32)
                    ((float*)C)[(row + r) * ldc + col] = vf;
                else
                    ((short*)C)[(row + r) * ldc + col] = f2bf(vf);
            }
        }
    }

    if (ssout) {
#pragma unroll
        for (int mc = 0; mc < MC; mc++)
#pragma unroll
            for (int r = 0; r < 4; r++) {
                float v = sq[mc][r];
                v += __shfl_xor(v, 1);
                v += __shfl_xor(v, 2);
                v += __shfl_xor(v, 4);
                v += __shfl_xor(v, 8);
                if (l15 == 0)
                    atomicAdd(&ssout[m0 + wr * (BM_ / 2) + mc * 16 + quad * 4 + r], v);
            }
    }
}

// ---------------- Flash attention: 128-key KV tiles ----------------
__global__ __launch_bounds__(256) void flash_attn_kernel(const short* __restrict__ q,
                                                         const short* __restrict__ k,
                                                         const short* __restrict__ vt,
                                                         int rs,
                                                         short* __restrict__ o) {
    int h = blockIdx.y;
    int q0 = blockIdx.x * 64;
    int t = threadIdx.x;
    int lane = t & 63, wid = t >> 6;
    int quad = lane >> 4, l15 = lane & 15;

    __shared__ short K2[2 * 128 * 32];    // [dc][key(128)][32]
    __shared__ short V2[4 * 64 * 32];     // [kc2][d(64)][32]
    __shared__ short Pw[4][2048];         // per-wave P; reused for O

    int ld4 = lane >> 2, lc8 = (lane & 3) * 8;

    s8v bq[2];
    int qrow = q0 + wid * 16 + l15;
#pragma unroll
    for (int c = 0; c < 2; c++) {
        s8v raw = *(const s8v*)(q + qrow * rs + h * HD + c * 32 + quad * 8);
#pragma unroll
        for (int j = 0; j < 8; j++) bq[c][j] = f2bf(0.125f * bf2f(raw[j]));
    }

    f4v o_acc[4] = {};
    float m_s = -INFINITY, l_s = 0.f;

    for (int kv0 = 0; kv0 < S; kv0 += 128) {
#pragma unroll
        for (int dc = 0; dc < 2; dc++)
#pragma unroll
            for (int i = 0; i < 2; i++)
                gload_lds16(k + (kv0 + wid * 32 + i * 16 + ld4) * rs + h * HD + dc * 32 + lc8,
                            K2 + dc * 4096 + (wid * 32 + i * 16) * 32);
#pragma unroll
        for (int kc2 = 0; kc2 < 4; kc2++)
            gload_lds16(vt + (h * HD + wid * 16 + ld4) * S + kv0 + kc2 * 32 + lc8,
                        V2 + kc2 * 2048 + (wid * 16) * 32);
        __syncthreads();

        f4v st[8];
#pragma unroll
        for (int kc = 0; kc < 8; kc++) {
            f4v a_ = (f4v){0.f, 0.f, 0.f, 0.f};
#pragma unroll
            for (int dc = 0; dc < 2; dc++) {
                s8v kf = *(const s8v*)(K2 + dc * 4096 + (kc * 16 + l15) * 32 + quad * 8);
                a_ = __builtin_amdgcn_mfma_f32_16x16x32_bf16(kf, bq[dc], a_, 0, 0, 0);
            }
            st[kc] = a_;
        }

        float mloc = -INFINITY;
#pragma unroll
        for (int kc = 0; kc < 8; kc++)
#pragma unroll
            for (int r = 0; r < 4; r++) mloc = fmaxf(mloc, st[kc][r]);
        mloc = fmaxf(mloc, __shfl_xor(mloc, 16));
        mloc = fmaxf(mloc, __shfl_xor(mloc, 32));
        float m_new = fmaxf(m_s, mloc);
        float alpha = __expf(m_s - m_new);
        float lloc = 0.f;
#pragma unroll
        for (int kc = 0; kc < 8; kc++)
#pragma unroll
            for (int r = 0; r < 4; r++) {
                float p = __expf(st[kc][r] - m_new);
                st[kc][r] = p;
                lloc += p;
            }
        lloc += __shfl_xor(lloc, 16);
        lloc += __shfl_xor(lloc, 32);
        l_s = l_s * alpha + lloc;
        m_s = m_new;
#pragma unroll
        for (int nd = 0; nd < 4; nd++)
#pragma unroll
            for (int r = 0; r < 4; r++) o_acc[nd][r] *= alpha;

#pragma unroll
        for (int kc = 0; kc < 8; kc++)
#pragma unroll
            for (int r = 0; r < 4; r++)
                Pw[wid][(kc >> 1) * 512 + l15 * 32 + (kc & 1) * 16 + quad * 4 + r] = f2bf(st[kc][r]);

#pragma unroll
        for (int nd = 0; nd < 4; nd++) {
#pragma unroll
            for (int kc2 = 0; kc2 < 4; kc2++) {
                s8v vf = *(const s8v*)(V2 + kc2 * 2048 + (nd * 16 + l15) * 32 + quad * 8);
                s8v pf = *(const s8v*)(Pw[wid] + kc2 * 512 + l15 * 32 + quad * 8);
                o_acc[nd] = __builtin_amdgcn_mfma_f32_16x16x32_bf16(vf, pf, o_acc[nd], 0, 0, 0);
            }
        }
        __syncthreads();
    }

    float inv = 1.f / l_s;
#pragma unroll
    for (int nd = 0; nd < 4; nd++)
#pragma unroll
        for (int r = 0; r < 4; r++)
            Pw[wid][l15 * 64 + nd * 16 + quad * 4 + r] = f2bf(o_acc[nd][r] * inv);

    int qr = lane >> 2, dc2 = (lane & 3) * 16;
    s8v x0 = *(const s8v*)(Pw[wid] + qr * 64 + dc2);
    s8v x1 = *(const s8v*)(Pw[wid] + qr * 64 + dc2 + 8);
    short* dst = o + (q0 + wid * 16 + qr) * H + h * HD + dc2;
    *(s8v*)(dst) = x0;
    *(s8v*)(dst + 8) = x1;
}

extern "C" void kernel_launch(void* const* d_in, const int* in_sizes, int n_in,
                              void* d_out, int out_size, void* d_ws, size_t ws_size,
                              hipStream_t stream) {
    const int SH = S * H;      // 2M
    const int WH = H * H;      // 1M
    const int WI = H * ISZ;    // 4M

    int* flag = (int*)d_ws;
    short* base = (short*)d_ws + 16;

    short* hidc   = base;               // 2M
    short* ctxc   = hidc + SH;          // 2M
    short* saqkvT = ctxc + SH;          // 3M
    short* sawoT  = saqkvT + 3 * WH;    // 1M
    short* caqkvT = sawoT + WH;         // 3M (γ_ca folded into first WH)
    short* cawoT  = caqkvT + 3 * WH;    // 1M
    short* wguT   = cawoT + WH;         // 8M interleaved [8192][1024], γ_mlp folded
    short* wdT    = wguT + 2 * WI;      // 4M
    short* xn     = wdT + WI;           // 2M
    short* qkv    = xn + SH;            // [S][3H]
    short* ao     = qkv + 3 * SH;
    short* h1     = ao + SH;
    short* gu     = qkv;                // [S][I] compact silu output (aliases qkv)
    short* h2     = qkv + 8 * SH;       // 2M
    short* vt     = h2 + SH;            // 2M  V^T [H][S]
    float* rowss1 = (float*)(vt + SH);  // S floats
    float* rowss2 = rowss1 + S;         // S floats

    dim3 blk(256);

    PreArgs pa;
    pa.hid = d_in[0]; pa.ctx = d_in[1];
    pa.sanw = d_in[2]; pa.canw = d_in[7]; pa.mlpnw = d_in[12];
    const void* wsrc[11] = {d_in[3], d_in[4], d_in[5], d_in[6],
                            d_in[8], d_in[9], d_in[10], d_in[11],
                            d_in[13], d_in[14], d_in[15]};
    short* wdst[11] = {saqkvT, saqkvT + WH, saqkvT + 2 * WH, sawoT,
                       caqkvT, caqkvT + WH, caqkvT + 2 * WH, cawoT,
                       wguT, wguT /*interleaved*/, wdT};
    for (int i = 0; i < 11; i++) { pa.w[i] = wsrc[i]; pa.wT[i] = wdst[i]; }
    pa.hidc = hidc; pa.ctxc = ctxc; pa.xn = xn;
    pa.rowss = rowss1;
    pa.flag_out = flag;
    const int pre_blocks = 2048 + 1024 + 2 + 8 * 1024 + 2 * 4096 + 4096;
    preamble_kernel<<<pre_blocks, blk, 0, stream>>>(pa);

    // ---- self-attention (xn = rmsnorm(hid) from preamble) ----
    gemm_bt_kernel<64, 128><<<dim3(S / 64, 3 * H / 128), blk, 0, stream>>>(
        xn, xn, 24, H, saqkvT, qkv, 3 * H, H, nullptr, nullptr, vt, 2 * H, nullptr,
        nullptr, nullptr);
    flash_attn_kernel<<<dim3(S / 64, NH), blk, 0, stream>>>(qkv, qkv + H, vt, 3 * H, ao);
    gemm_bt_kernel<64, 64><<<dim3(S / 64, H / 64), blk, 0, stream>>>(
        ao, ao, 16, H, sawoT, h1, H, H, hidc, nullptr, nullptr, 0, nullptr,
        nullptr, rowss1);                                  // h1 + its row sumsq

    // ---- cross-attention (q = s_r·(h1·γca⊙wq), kv from ctxc) ----
    gemm_bt_kernel<64, 128><<<dim3(S / 64, 3 * H / 128), blk, 0, stream>>>(
        h1, ctxc, 8, H, caqkvT, qkv, 3 * H, H, nullptr, nullptr, vt, 2 * H, nullptr,
        rowss1, nullptr);
    flash_attn_kernel<<<dim3(S / 64, NH), blk, 0, stream>>>(qkv, qkv + H, vt, 3 * H, ao);
    gemm_bt_kernel<64, 64><<<dim3(S / 64, H / 64), blk, 0, stream>>>(
        ao, ao, 16, H, cawoT, h2, H, H, h1, nullptr, nullptr, 0, nullptr,
        nullptr, rowss2);                                  // h2 + its row sumsq

    // ---- MLP: scaled gate/up + fused SiLU·mul, then down ----
    gemm_bt_kernel<128, 128><<<dim3(S / 128, 2 * ISZ / 128), blk, 0, stream>>>(
        h2, h2, 64, H, wguT, nullptr, 2 * ISZ, H, nullptr, nullptr, nullptr, 0, gu,
        rowss2, nullptr);
    gemm_bt_kernel<64, 64><<<dim3(S / 64, H / 64), blk, 0, stream>>>(
        gu, gu, 16, ISZ, wdT, d_out, H, ISZ, h2, flag, nullptr, 0, nullptr,
        nullptr, nullptr);
}